// Round 11
// baseline (165.840 us; speedup 1.0000x reference)
//
#include <hip/hip_runtime.h>
#include <math.h>

#define NELEC 10
#define NSPIN 2
#define NPER 5
#define DIM 3
#define NION 2
#define DP 32
#define NDENSE 64
#define NPERM 120
#define RS 324   // G row stride (words): rows at pool+160+324j -> start bank 4j -> the 5
                 // selectable rows hit disjoint bank quads; b128-aligned. 0 conflicts (R5-R10).
#define HTS 124  // HT row stride (words): phase-2 b128 reads at banks {8g%32} -> 2 addrs per
                 // bank-quad (free, m136); phase-1 b32 writes lane-consecutive -> 2/bank free.

// LDS pool with live-range overlay (R10-validated):
//   stage A (stages 1-2 + phase-1 reads): s1e[160] @ 0, G[5][324] @ 160..1780
//   stage B (phase-2):                    HT[64][124] @ 0..7936
// h is carried in REGISTERS across the A->B transition, so G can be overwritten.
#define POOL_WORDS (NDENSE * HTS)

// tanh(x) = 1 - 2*rcp(exp(2x)+1): v_exp + v_rcp, ~1-2 ulp, exact at saturation. Validated R5-R10.
__device__ __forceinline__ float fast_tanh(float x) {
    float e = __expf(2.0f * x);
    return 1.0f - 2.0f * __builtin_amdgcn_rcpf(e + 1.0f);
}

__device__ __forceinline__ unsigned pick_remove(unsigned& el, int d) {
    unsigned v = (el >> (4 * d)) & 0xFu;
    unsigned low = el & ((1u << (4 * d)) - 1u);
    el = low | ((el >> (4 * (d + 1))) << (4 * d));
    return v;
}

// ---------------- main: one block per (batch, spin), 2 waves (R8/R10-validated) ----------------
// R10 post-mortem: occupancy pushes (R9, R10) both failed to move dur (~106us, VALU 60%).
// Timeline model: k+1 prefetch = ~128 issue-cycles of slack < ~200cyc global L1 latency
// -> every phase-2 iteration stalls ~80cyc on vmcnt. THIS round: depth-2 software
// pipeline (256 cycles slack > 200) for both HT and w1 streams. Only change vs R10.
__global__ __launch_bounds__(128, 1) void antisym_kern(
    const float* __restrict__ elec_pos, const float* __restrict__ ion_pos,
    const float* __restrict__ bf_w, const float* __restrict__ bf_b,
    const float* __restrict__ w0, const float* __restrict__ b0,
    const float* __restrict__ w1, const float* __restrict__ b1,
    const float* __restrict__ w2,
    float* __restrict__ psum, int B)
{
    const int b = blockIdx.x;
    const int s = blockIdx.y;
    const int t = threadIdx.x;
    const int wave = t >> 6, lane = t & 63;

    __shared__ __align__(16) float pool[POOL_WORDS];    // 31744 B, overlaid (see above)
    __shared__ double red_h[2];
    __shared__ double red_j[2];

    float* s1e = pool;                                  // [160]      (stage A)
    #define GROW(j) (pool + 160 + (j) * RS)             // G[j][·]    (stage A)
    #define HTROW(k) (pool + (k) * HTS)                 // HT[k][·]   (stage B)

    // ---- stage 1: stream_1e = tanh(feats @ bf_w + bf_b) for this spin's 5 electrons ----
    const float* ep = elec_pos + (b * NELEC + s * NPER) * DIM;
    const float i0x = ion_pos[0], i0y = ion_pos[1], i0z = ion_pos[2];
    const float i1x = ion_pos[3], i1y = ion_pos[4], i1z = ion_pos[5];
    for (int idx = t; idx < NPER * DP; idx += 128) {
        int j = idx >> 5, c = idx & 31;
        float ex = ep[j * 3 + 0], ey = ep[j * 3 + 1], ez = ep[j * 3 + 2];
        float dx0 = ex - i0x, dy0 = ey - i0y, dz0 = ez - i0z;
        float dx1 = ex - i1x, dy1 = ey - i1y, dz1 = ez - i1z;
        float n0 = sqrtf(dx0 * dx0 + dy0 * dy0 + dz0 * dz0);
        float n1 = sqrtf(dx1 * dx1 + dy1 * dy1 + dz1 * dz1);
        float acc = bf_b[c];
        acc += dx0 * bf_w[0 * DP + c];
        acc += dy0 * bf_w[1 * DP + c];
        acc += dz0 * bf_w[2 * DP + c];
        acc += dx1 * bf_w[3 * DP + c];
        acc += dy1 * bf_w[4 * DP + c];
        acc += dz1 * bf_w[5 * DP + c];
        acc += n0 * bf_w[6 * DP + c];
        acc += n1 * bf_w[7 * DP + c];
        s1e[idx] = fast_tanh(acc);
    }
    __syncthreads();

    // ---- stage 2: G[j][i*64+c] = s1e[j][:] @ w0[s][32i:32i+32, c] (R5-R10 validated) ----
    const float* w0s = w0 + s * (NPER * DP) * NDENSE;   // [160][64]
    for (int j = wave; j < NPER; j += 2) {
        float4 sv4[8];
        #pragma unroll
        for (int q = 0; q < 8; q++) sv4[q] = *(const float4*)(s1e + j * DP + q * 4);
        #pragma unroll
        for (int i = 0; i < NPER; i++) {
            float acc = 0.f;
            #pragma unroll
            for (int q = 0; q < 8; q++) {
                const float* wb = w0s + (i * DP + q * 4) * NDENSE + lane;  // coalesced
                acc += sv4[q].x * wb[0 * NDENSE];
                acc += sv4[q].y * wb[1 * NDENSE];
                acc += sv4[q].z * wb[2 * NDENSE];
                acc += sv4[q].w * wb[3 * NDENSE];
            }
            GROW(j)[i * NDENSE + lane] = acc;
        }
    }
    __syncthreads();

    const float* b0s = b0 + s * NDENSE;
    const float* w2s = w2 + s * NDENSE;     // w2 is [s][64][1]

    // ---- stage 3 phase 1: lane = perm. h_p built ENTIRELY in registers (G still live) ----
    const int pid = wave * 60 + lane;
    float sign = 0.f;
    int p0 = 0, p1 = 0, p2 = 0, p3 = 0, p4 = 0;
    if (lane < 60) {
        int p = pid;
        unsigned el = 0x43210u;
        int d0 = p / 24; p -= d0 * 24;
        int d1 = p / 6;  p -= d1 * 6;
        int d2 = p / 2;  p -= d2 * 2;
        int d3 = p;
        p0 = pick_remove(el, d0);
        p1 = pick_remove(el, d1);
        p2 = pick_remove(el, d2);
        p3 = pick_remove(el, d3);
        p4 = el & 0xF;
        sign = ((d0 + d1 + d2 + d3) & 1) ? -1.f : 1.f;
    }
    const float* g0 = GROW(p0) + 0 * NDENSE;
    const float* g1 = GROW(p1) + 1 * NDENSE;
    const float* g2 = GROW(p2) + 2 * NDENSE;
    const float* g3 = GROW(p3) + 3 * NDENSE;
    const float* g4 = GROW(p4) + 4 * NDENSE;

    float h[NDENSE];                        // constant-indexed -> VGPR-resident
    float hdot = 0.f;
    #pragma unroll
    for (int cc = 0; cc < NDENSE / 4; cc++) {
        float4 a = *(const float4*)(b0s + cc * 4);                    // uniform -> s_load
        float4 q;
        q = *(const float4*)(g0 + cc * 4); a.x += q.x; a.y += q.y; a.z += q.z; a.w += q.w;
        q = *(const float4*)(g1 + cc * 4); a.x += q.x; a.y += q.y; a.z += q.z; a.w += q.w;
        q = *(const float4*)(g2 + cc * 4); a.x += q.x; a.y += q.y; a.z += q.z; a.w += q.w;
        q = *(const float4*)(g3 + cc * 4); a.x += q.x; a.y += q.y; a.z += q.z; a.w += q.w;
        q = *(const float4*)(g4 + cc * 4); a.x += q.x; a.y += q.y; a.z += q.z; a.w += q.w;
        float t0 = fast_tanh(a.x), t1 = fast_tanh(a.y), t2 = fast_tanh(a.z), t3 = fast_tanh(a.w);
        h[cc * 4 + 0] = t0; h[cc * 4 + 1] = t1; h[cc * 4 + 2] = t2; h[cc * 4 + 3] = t3;
        hdot += t0 * w2s[cc * 4 + 0] + t1 * w2s[cc * 4 + 1]
              + t2 * w2s[cc * 4 + 2] + t3 * w2s[cc * 4 + 3];
    }

    double dvh = (double)(sign * hdot);     // sign=0 for lanes 60-63
    #pragma unroll
    for (int off = 32; off > 0; off >>= 1) dvh += __shfl_down(dvh, off, 64);
    if (lane == 0) red_h[wave] = dvh;

    __syncthreads();                        // ALL G reads complete -> pool reusable

    // park h transposed: HT[k][pid] (b32 writes, consecutive pids -> 2 lanes/bank = free)
    if (lane < 60) {
        #pragma unroll
        for (int k = 0; k < NDENSE; k++) HTROW(k)[pid] = h[k];
    }
    __syncthreads();                        // HT visible cross-wave

    // ---- stage 3 phase 2: 8x8 register-tiled GEMM V[120x64] = H @ W1, DEPTH-2 pipeline ----
    // wave0: perms 0..63 (pb=8*pg). wave1: perms 56..119; pg==0 duplicates 56-63 -> sgn 0.
    const int pg = lane >> 3, jg = lane & 7;
    const int pb = wave ? (56 + 8 * pg) : (8 * pg);
    const float* w1s = w1 + s * NDENSE * NDENSE;
    const float* b1s = b1 + s * NDENSE;
    const float* wgp = w1s + 8 * jg;        // this lane's j-octet in w1 row k

    float v[8][8];
    #pragma unroll
    for (int i = 0; i < 8; i++)
        #pragma unroll
        for (int r = 0; r < 8; r++) v[i][r] = 0.f;

    // depth-2 software pipeline: load->use distance = 2 iterations (~256 issue cycles)
    // > ~200cyc global L1 latency and > ~120cyc LDS latency.
    float4 haP[2], hbP[2], waP[2], wbP[2];
    haP[0] = *(const float4*)(&HTROW(0)[pb]);
    hbP[0] = *(const float4*)(&HTROW(0)[pb + 4]);
    waP[0] = *(const float4*)(wgp);
    wbP[0] = *(const float4*)(wgp + 4);
    haP[1] = *(const float4*)(&HTROW(1)[pb]);
    hbP[1] = *(const float4*)(&HTROW(1)[pb + 4]);
    waP[1] = *(const float4*)(wgp + NDENSE);
    wbP[1] = *(const float4*)(wgp + NDENSE + 4);

    #pragma unroll 4
    for (int k = 0; k < NDENSE; k++) {
        const int sl = k & 1;
        const float4 ha = haP[sl], hb = hbP[sl], wa = waP[sl], wb = wbP[sl];
        if (k + 2 < NDENSE) {               // refill the slot just consumed (for k+2)
            haP[sl] = *(const float4*)(&HTROW(k + 2)[pb]);
            hbP[sl] = *(const float4*)(&HTROW(k + 2)[pb + 4]);
            waP[sl] = *(const float4*)(wgp + (k + 2) * NDENSE);
            wbP[sl] = *(const float4*)(wgp + (k + 2) * NDENSE + 4);
        }
        const float hv[8] = {ha.x, ha.y, ha.z, ha.w, hb.x, hb.y, hb.z, hb.w};
        const float wv[8] = {wa.x, wa.y, wa.z, wa.w, wb.x, wb.y, wb.z, wb.w};
        #pragma unroll
        for (int i = 0; i < 8; i++)
            #pragma unroll
            for (int r = 0; r < 8; r++)
                v[i][r] = fmaf(hv[i], wv[r], v[i][r]);
    }

    // epilogue: lanesum = sum_i sgn_i * sum_r tanh(v[i][r]+b1[j]) * w2[j]
    float4 b1a = *(const float4*)(b1s + 8 * jg);
    float4 b1b = *(const float4*)(b1s + 8 * jg + 4);
    float4 w2a = *(const float4*)(w2s + 8 * jg);
    float4 w2b = *(const float4*)(w2s + 8 * jg + 4);
    const float b1v[8] = {b1a.x, b1a.y, b1a.z, b1a.w, b1b.x, b1b.y, b1b.z, b1b.w};
    const float w2v[8] = {w2a.x, w2a.y, w2a.z, w2a.w, w2b.x, w2b.y, w2b.z, w2b.w};

    float lanesum = 0.f;
    #pragma unroll
    for (int i = 0; i < 8; i++) {
        int p = pb + i;                      // Lehmer parity
        int d0 = p / 24;  int r0 = p - 24 * d0;
        int d1 = r0 / 6;  int r1 = r0 - 6 * d1;
        int d2 = r1 >> 1; int d3 = r1 & 1;
        float sgn = ((d0 + d1 + d2 + d3) & 1) ? -1.f : 1.f;
        if (wave == 1 && pg == 0) sgn = 0.f; // duplicate tile (perms 56-63)
        float si = 0.f;
        #pragma unroll
        for (int r = 0; r < 8; r++)
            si = fmaf(fast_tanh(v[i][r] + b1v[r]), w2v[r], si);
        lanesum = fmaf(sgn, si, lanesum);
    }

    double dvj = (double)lanesum;
    #pragma unroll
    for (int off = 32; off > 0; off >>= 1) dvj += __shfl_down(dvj, off, 64);
    if (lane == 0) red_j[wave] = dvj;
    __syncthreads();
    if (t == 0)
        psum[s * B + b] = (float)((red_h[0] + red_h[1]) + (red_j[0] + red_j[1]));
    // b2 omitted: sum_p sign_p = 0 kills it exactly.
}

// ---------------- combine: log|ps0*ps1| + jastrow (validated form) ----------------
__global__ void combine_kern(const float* __restrict__ psum,
                             const float* __restrict__ elec_pos,
                             const float* __restrict__ ion_pos,
                             const float* __restrict__ jk,
                             float* __restrict__ out, int B)
{
    int b = blockIdx.x * 256 + threadIdx.x;
    if (b >= B) return;
    const float i0x = ion_pos[0], i0y = ion_pos[1], i0z = ion_pos[2];
    const float i1x = ion_pos[3], i1y = ion_pos[4], i1z = ion_pos[5];
    const float j0 = jk[0], j1 = jk[1];
    const float* ep = elec_pos + b * NELEC * DIM;
    float jas = 0.f;
    #pragma unroll
    for (int e = 0; e < NELEC; e++) {
        float ex = ep[e * 3 + 0], ey = ep[e * 3 + 1], ez = ep[e * 3 + 2];
        float dx0 = ex - i0x, dy0 = ey - i0y, dz0 = ez - i0z;
        float dx1 = ex - i1x, dy1 = ey - i1y, dz1 = ez - i1z;
        jas += j0 * sqrtf(dx0 * dx0 + dy0 * dy0 + dz0 * dz0);
        jas += j1 * sqrtf(dx1 * dx1 + dy1 * dy1 + dz1 * dz1);
    }
    float ps0 = psum[b], ps1 = psum[B + b];
    out[b] = logf(fabsf(ps0 * ps1)) - jas;
}

extern "C" void kernel_launch(void* const* d_in, const int* in_sizes, int n_in,
                              void* d_out, int out_size, void* d_ws, size_t ws_size,
                              hipStream_t stream) {
    const float* elec_pos = (const float*)d_in[0];
    const float* ion_pos  = (const float*)d_in[1];
    const float* bf_w     = (const float*)d_in[2];
    const float* bf_b     = (const float*)d_in[3];
    const float* w0       = (const float*)d_in[4];
    const float* b0       = (const float*)d_in[5];
    const float* w1       = (const float*)d_in[6];
    const float* b1       = (const float*)d_in[7];
    const float* w2       = (const float*)d_in[8];
    const float* jk       = (const float*)d_in[10];
    float* out = (float*)d_out;

    const int B = in_sizes[0] / (NELEC * DIM);   // 2048

    float* psum = (float*)d_ws;                  // [2][B]

    hipLaunchKernelGGL(antisym_kern,
                       dim3(B, NSPIN), dim3(128), 0, stream,
                       elec_pos, ion_pos, bf_w, bf_b, w0, b0, w1, b1, w2, psum, B);
    hipLaunchKernelGGL(combine_kern,
                       dim3((B + 255) / 256), dim3(256), 0, stream,
                       psum, elec_pos, ion_pos, jk, out, B);
}

// Round 12
// 161.740 us; speedup vs baseline: 1.0253x; 1.0253x over previous
//
#include <hip/hip_runtime.h>
#include <math.h>

#define NELEC 10
#define NSPIN 2
#define NPER 5
#define DIM 3
#define NION 2
#define DP 32
#define NDENSE 64
#define NPERM 120
#define RS 324   // G row stride (words): rows at pool+160+324j -> start bank 4j -> the 5
                 // selectable rows hit disjoint bank quads; b128-aligned. 0 conflicts (R5-R11).
#define HTS 124  // HT row stride (words): phase-2 b128 reads at banks {8g%32} -> 2 addrs per
                 // bank-quad (free, m136); phase-1 b32 writes lane-consecutive -> 2/bank free.

// LDS pool with live-range overlay (R10-validated):
//   stage A (stages 1-2 + phase-1 reads): s1e[160] @ 0, G[5][324] @ 160..1780
//   stage B (phase-2):                    HT[64][124] @ 0..7936
#define POOL_WORDS (NDENSE * HTS)

typedef float v2f __attribute__((ext_vector_type(2)));
typedef float v4f __attribute__((ext_vector_type(4)));

// Packed fp32 FMA (VOP3P). acc = (a_lo, a_hi) over the PERM direction; hp = h-pair
// (both halves used); w broadcast from one half of its pair via op_sel:
//  LO variant (w at pair.lo): res.lo = hp.lo*w + acc.lo ; res.hi = hp.hi*w + acc.hi
//  HI variant (w at pair.hi): same with S1.hi.
// Bit-identical to the scalar v_fma sequence - pure encoding change, 2 FMAs/instr.
#define PK_FMA_LO(acc, hp, wp) \
    asm("v_pk_fma_f32 %0, %1, %2, %0 op_sel_hi:[1,0,1]" : "+v"(acc) : "v"(hp), "v"(wp))
#define PK_FMA_HI(acc, hp, wp) \
    asm("v_pk_fma_f32 %0, %1, %2, %0 op_sel:[0,1,0] op_sel_hi:[1,1,1]" : "+v"(acc) : "v"(hp), "v"(wp))

// tanh(x) = 1 - 2*rcp(exp(2x)+1): v_exp + v_rcp, ~1-2 ulp, exact at saturation. Validated R5-R11.
__device__ __forceinline__ float fast_tanh(float x) {
    float e = __expf(2.0f * x);
    return 1.0f - 2.0f * __builtin_amdgcn_rcpf(e + 1.0f);
}

__device__ __forceinline__ unsigned pick_remove(unsigned& el, int d) {
    unsigned v = (el >> (4 * d)) & 0xFu;
    unsigned low = el & ((1u << (4 * d)) - 1u);
    el = low | ((el >> (4 * (d + 1))) << (4 * d));
    return v;
}

// ---------------- main: one block per (batch, spin), 2 waves (R10-validated base) ----------------
// R11 post-mortem: manual depth-2 pipelining REGRESSED (118 vs 106) - third failed
// stall-reduction attempt; compiler already schedules R10 well. This round cuts ISSUE
// count instead: phase-2 inner loop 64 v_fma -> 32 v_pk_fma_f32 (packed fp32, the
// reason MI355X lists 157.3 TF). Everything else byte-identical to R10.
__global__ __launch_bounds__(128, 1) void antisym_kern(
    const float* __restrict__ elec_pos, const float* __restrict__ ion_pos,
    const float* __restrict__ bf_w, const float* __restrict__ bf_b,
    const float* __restrict__ w0, const float* __restrict__ b0,
    const float* __restrict__ w1, const float* __restrict__ b1,
    const float* __restrict__ w2,
    float* __restrict__ psum, int B)
{
    const int b = blockIdx.x;
    const int s = blockIdx.y;
    const int t = threadIdx.x;
    const int wave = t >> 6, lane = t & 63;

    __shared__ __align__(16) float pool[POOL_WORDS];    // 31744 B, overlaid (see above)
    __shared__ double red_h[2];
    __shared__ double red_j[2];

    float* s1e = pool;                                  // [160]      (stage A)
    #define GROW(j) (pool + 160 + (j) * RS)             // G[j][·]    (stage A)
    #define HTROW(k) (pool + (k) * HTS)                 // HT[k][·]   (stage B)

    // ---- stage 1: stream_1e = tanh(feats @ bf_w + bf_b) for this spin's 5 electrons ----
    const float* ep = elec_pos + (b * NELEC + s * NPER) * DIM;
    const float i0x = ion_pos[0], i0y = ion_pos[1], i0z = ion_pos[2];
    const float i1x = ion_pos[3], i1y = ion_pos[4], i1z = ion_pos[5];
    for (int idx = t; idx < NPER * DP; idx += 128) {
        int j = idx >> 5, c = idx & 31;
        float ex = ep[j * 3 + 0], ey = ep[j * 3 + 1], ez = ep[j * 3 + 2];
        float dx0 = ex - i0x, dy0 = ey - i0y, dz0 = ez - i0z;
        float dx1 = ex - i1x, dy1 = ey - i1y, dz1 = ez - i1z;
        float n0 = sqrtf(dx0 * dx0 + dy0 * dy0 + dz0 * dz0);
        float n1 = sqrtf(dx1 * dx1 + dy1 * dy1 + dz1 * dz1);
        float acc = bf_b[c];
        acc += dx0 * bf_w[0 * DP + c];
        acc += dy0 * bf_w[1 * DP + c];
        acc += dz0 * bf_w[2 * DP + c];
        acc += dx1 * bf_w[3 * DP + c];
        acc += dy1 * bf_w[4 * DP + c];
        acc += dz1 * bf_w[5 * DP + c];
        acc += n0 * bf_w[6 * DP + c];
        acc += n1 * bf_w[7 * DP + c];
        s1e[idx] = fast_tanh(acc);
    }
    __syncthreads();

    // ---- stage 2: G[j][i*64+c] = s1e[j][:] @ w0[s][32i:32i+32, c] (R5-R11 validated) ----
    const float* w0s = w0 + s * (NPER * DP) * NDENSE;   // [160][64]
    for (int j = wave; j < NPER; j += 2) {
        float4 sv4[8];
        #pragma unroll
        for (int q = 0; q < 8; q++) sv4[q] = *(const float4*)(s1e + j * DP + q * 4);
        #pragma unroll
        for (int i = 0; i < NPER; i++) {
            float acc = 0.f;
            #pragma unroll
            for (int q = 0; q < 8; q++) {
                const float* wb = w0s + (i * DP + q * 4) * NDENSE + lane;  // coalesced
                acc += sv4[q].x * wb[0 * NDENSE];
                acc += sv4[q].y * wb[1 * NDENSE];
                acc += sv4[q].z * wb[2 * NDENSE];
                acc += sv4[q].w * wb[3 * NDENSE];
            }
            GROW(j)[i * NDENSE + lane] = acc;
        }
    }
    __syncthreads();

    const float* b0s = b0 + s * NDENSE;
    const float* w2s = w2 + s * NDENSE;     // w2 is [s][64][1]

    // ---- stage 3 phase 1: lane = perm. h_p built ENTIRELY in registers (G still live) ----
    const int pid = wave * 60 + lane;
    float sign = 0.f;
    int p0 = 0, p1 = 0, p2 = 0, p3 = 0, p4 = 0;
    if (lane < 60) {
        int p = pid;
        unsigned el = 0x43210u;
        int d0 = p / 24; p -= d0 * 24;
        int d1 = p / 6;  p -= d1 * 6;
        int d2 = p / 2;  p -= d2 * 2;
        int d3 = p;
        p0 = pick_remove(el, d0);
        p1 = pick_remove(el, d1);
        p2 = pick_remove(el, d2);
        p3 = pick_remove(el, d3);
        p4 = el & 0xF;
        sign = ((d0 + d1 + d2 + d3) & 1) ? -1.f : 1.f;
    }
    const float* g0 = GROW(p0) + 0 * NDENSE;
    const float* g1 = GROW(p1) + 1 * NDENSE;
    const float* g2 = GROW(p2) + 2 * NDENSE;
    const float* g3 = GROW(p3) + 3 * NDENSE;
    const float* g4 = GROW(p4) + 4 * NDENSE;

    float h[NDENSE];                        // constant-indexed -> VGPR-resident
    float hdot = 0.f;
    #pragma unroll
    for (int cc = 0; cc < NDENSE / 4; cc++) {
        float4 a = *(const float4*)(b0s + cc * 4);                    // uniform -> s_load
        float4 q;
        q = *(const float4*)(g0 + cc * 4); a.x += q.x; a.y += q.y; a.z += q.z; a.w += q.w;
        q = *(const float4*)(g1 + cc * 4); a.x += q.x; a.y += q.y; a.z += q.z; a.w += q.w;
        q = *(const float4*)(g2 + cc * 4); a.x += q.x; a.y += q.y; a.z += q.z; a.w += q.w;
        q = *(const float4*)(g3 + cc * 4); a.x += q.x; a.y += q.y; a.z += q.z; a.w += q.w;
        q = *(const float4*)(g4 + cc * 4); a.x += q.x; a.y += q.y; a.z += q.z; a.w += q.w;
        float t0 = fast_tanh(a.x), t1 = fast_tanh(a.y), t2 = fast_tanh(a.z), t3 = fast_tanh(a.w);
        h[cc * 4 + 0] = t0; h[cc * 4 + 1] = t1; h[cc * 4 + 2] = t2; h[cc * 4 + 3] = t3;
        hdot += t0 * w2s[cc * 4 + 0] + t1 * w2s[cc * 4 + 1]
              + t2 * w2s[cc * 4 + 2] + t3 * w2s[cc * 4 + 3];
    }

    double dvh = (double)(sign * hdot);     // sign=0 for lanes 60-63
    #pragma unroll
    for (int off = 32; off > 0; off >>= 1) dvh += __shfl_down(dvh, off, 64);
    if (lane == 0) red_h[wave] = dvh;

    __syncthreads();                        // ALL G reads complete -> pool reusable

    // park h transposed: HT[k][pid] (b32 writes, consecutive pids -> 2 lanes/bank = free)
    if (lane < 60) {
        #pragma unroll
        for (int k = 0; k < NDENSE; k++) HTROW(k)[pid] = h[k];
    }
    __syncthreads();                        // HT visible cross-wave

    // ---- stage 3 phase 2: 8x8 tile GEMM V[120x64] = H @ W1, packed-fp32 FMA ----
    // wave0: perms 0..63 (pb=8*pg). wave1: perms 56..119; pg==0 duplicates 56-63 -> sgn 0.
    // Accumulator paired over the perm direction: vp[ip][r] = (v[2ip][r], v[2ip+1][r]).
    // h-pairs come free from the b128 load (consecutive aligned VGPRs); w scalars are
    // broadcast from their pair via op_sel -> 32 v_pk_fma_f32 per k, zero extra movs.
    const int pg = lane >> 3, jg = lane & 7;
    const int pb = wave ? (56 + 8 * pg) : (8 * pg);
    const float* w1s = w1 + s * NDENSE * NDENSE;
    const float* b1s = b1 + s * NDENSE;
    const float* wgp = w1s + 8 * jg;        // this lane's j-octet in w1 row k

    v2f vp[4][8];
    #pragma unroll
    for (int ip = 0; ip < 4; ip++)
        #pragma unroll
        for (int r = 0; r < 8; r++) vp[ip][r] = (v2f)(0.f);

    v4f ha_n = *(const v4f*)(&HTROW(0)[pb]);
    v4f hb_n = *(const v4f*)(&HTROW(0)[pb + 4]);
    v4f wa_n = *(const v4f*)(wgp);
    v4f wb_n = *(const v4f*)(wgp + 4);
    #pragma unroll 4
    for (int k = 0; k < NDENSE; k++) {
        const v4f ha = ha_n, hb = hb_n, wa = wa_n, wb = wb_n;
        if (k + 1 < NDENSE) {               // R10-validated k+1 prefetch
            ha_n = *(const v4f*)(&HTROW(k + 1)[pb]);
            hb_n = *(const v4f*)(&HTROW(k + 1)[pb + 4]);
            wa_n = *(const v4f*)(wgp + (k + 1) * NDENSE);
            wb_n = *(const v4f*)(wgp + (k + 1) * NDENSE + 4);
        }
        v2f hp[4] = {ha.xy, ha.zw, hb.xy, hb.zw};   // perm pairs (subreg views)
        v2f wp[4] = {wa.xy, wa.zw, wb.xy, wb.zw};   // j pairs
        #pragma unroll
        for (int ip = 0; ip < 4; ip++) {
            PK_FMA_LO(vp[ip][0], hp[ip], wp[0]);
            PK_FMA_HI(vp[ip][1], hp[ip], wp[0]);
            PK_FMA_LO(vp[ip][2], hp[ip], wp[1]);
            PK_FMA_HI(vp[ip][3], hp[ip], wp[1]);
            PK_FMA_LO(vp[ip][4], hp[ip], wp[2]);
            PK_FMA_HI(vp[ip][5], hp[ip], wp[2]);
            PK_FMA_LO(vp[ip][6], hp[ip], wp[3]);
            PK_FMA_HI(vp[ip][7], hp[ip], wp[3]);
        }
    }

    // epilogue: lanesum = sum_i sgn_i * sum_r tanh(v[i][r]+b1[j]) * w2[j]
    float4 b1a = *(const float4*)(b1s + 8 * jg);
    float4 b1b = *(const float4*)(b1s + 8 * jg + 4);
    float4 w2a = *(const float4*)(w2s + 8 * jg);
    float4 w2b = *(const float4*)(w2s + 8 * jg + 4);
    const float b1v[8] = {b1a.x, b1a.y, b1a.z, b1a.w, b1b.x, b1b.y, b1b.z, b1b.w};
    const float w2v[8] = {w2a.x, w2a.y, w2a.z, w2a.w, w2b.x, w2b.y, w2b.z, w2b.w};

    float lanesum = 0.f;
    #pragma unroll
    for (int i = 0; i < 8; i++) {
        int p = pb + i;                      // Lehmer parity
        int d0 = p / 24;  int r0 = p - 24 * d0;
        int d1 = r0 / 6;  int r1 = r0 - 6 * d1;
        int d2 = r1 >> 1; int d3 = r1 & 1;
        float sgn = ((d0 + d1 + d2 + d3) & 1) ? -1.f : 1.f;
        if (wave == 1 && pg == 0) sgn = 0.f; // duplicate tile (perms 56-63)
        float si = 0.f;
        #pragma unroll
        for (int r = 0; r < 8; r++) {
            float vir = (i & 1) ? vp[i >> 1][r].y : vp[i >> 1][r].x;
            si = fmaf(fast_tanh(vir + b1v[r]), w2v[r], si);
        }
        lanesum = fmaf(sgn, si, lanesum);
    }

    double dvj = (double)lanesum;
    #pragma unroll
    for (int off = 32; off > 0; off >>= 1) dvj += __shfl_down(dvj, off, 64);
    if (lane == 0) red_j[wave] = dvj;
    __syncthreads();
    if (t == 0)
        psum[s * B + b] = (float)((red_h[0] + red_h[1]) + (red_j[0] + red_j[1]));
    // b2 omitted: sum_p sign_p = 0 kills it exactly.
}

// ---------------- combine: log|ps0*ps1| + jastrow (validated form) ----------------
__global__ void combine_kern(const float* __restrict__ psum,
                             const float* __restrict__ elec_pos,
                             const float* __restrict__ ion_pos,
                             const float* __restrict__ jk,
                             float* __restrict__ out, int B)
{
    int b = blockIdx.x * 256 + threadIdx.x;
    if (b >= B) return;
    const float i0x = ion_pos[0], i0y = ion_pos[1], i0z = ion_pos[2];
    const float i1x = ion_pos[3], i1y = ion_pos[4], i1z = ion_pos[5];
    const float j0 = jk[0], j1 = jk[1];
    const float* ep = elec_pos + b * NELEC * DIM;
    float jas = 0.f;
    #pragma unroll
    for (int e = 0; e < NELEC; e++) {
        float ex = ep[e * 3 + 0], ey = ep[e * 3 + 1], ez = ep[e * 3 + 2];
        float dx0 = ex - i0x, dy0 = ey - i0y, dz0 = ez - i0z;
        float dx1 = ex - i1x, dy1 = ey - i1y, dz1 = ez - i1z;
        jas += j0 * sqrtf(dx0 * dx0 + dy0 * dy0 + dz0 * dz0);
        jas += j1 * sqrtf(dx1 * dx1 + dy1 * dy1 + dz1 * dz1);
    }
    float ps0 = psum[b], ps1 = psum[B + b];
    out[b] = logf(fabsf(ps0 * ps1)) - jas;
}

extern "C" void kernel_launch(void* const* d_in, const int* in_sizes, int n_in,
                              void* d_out, int out_size, void* d_ws, size_t ws_size,
                              hipStream_t stream) {
    const float* elec_pos = (const float*)d_in[0];
    const float* ion_pos  = (const float*)d_in[1];
    const float* bf_w     = (const float*)d_in[2];
    const float* bf_b     = (const float*)d_in[3];
    const float* w0       = (const float*)d_in[4];
    const float* b0       = (const float*)d_in[5];
    const float* w1       = (const float*)d_in[6];
    const float* b1       = (const float*)d_in[7];
    const float* w2       = (const float*)d_in[8];
    const float* jk       = (const float*)d_in[10];
    float* out = (float*)d_out;

    const int B = in_sizes[0] / (NELEC * DIM);   // 2048

    float* psum = (float*)d_ws;                  // [2][B]

    hipLaunchKernelGGL(antisym_kern,
                       dim3(B, NSPIN), dim3(128), 0, stream,
                       elec_pos, ion_pos, bf_w, bf_b, w0, b0, w1, b1, w2, psum, B);
    hipLaunchKernelGGL(combine_kern,
                       dim3((B + 255) / 256), dim3(256), 0, stream,
                       psum, elec_pos, ion_pos, jk, out, B);
}

// Round 13
// 155.539 us; speedup vs baseline: 1.0662x; 1.0399x over previous
//
#include <hip/hip_runtime.h>
#include <math.h>

#define NELEC 10
#define NSPIN 2
#define NPER 5
#define DIM 3
#define NION 2
#define DP 32
#define NDENSE 64
#define NPERM 120
#define RS 324   // G row stride (words): the 5 selectable rows land on disjoint bank quads.
#define HTS 124  // HT row stride (words): reads 2 addrs/bank-quad (free, m136); writes 2/bank free.

// Per-spin LDS pool with live-range overlay (R10/R12-validated):
//   stage A: s1e[160] @ 0, G[5][324] @ 160..1780
//   stage B: HT[64][124] @ 0..7936
#define POOL_WORDS (NDENSE * HTS)

typedef float v2f __attribute__((ext_vector_type(2)));
typedef float v4f __attribute__((ext_vector_type(4)));

// Packed fp32 FMA (VOP3P), bit-identical to scalar v_fma pairs (R12-validated).
#define PK_FMA_LO(acc, hp, wp) \
    asm("v_pk_fma_f32 %0, %1, %2, %0 op_sel_hi:[1,0,1]" : "+v"(acc) : "v"(hp), "v"(wp))
#define PK_FMA_HI(acc, hp, wp) \
    asm("v_pk_fma_f32 %0, %1, %2, %0 op_sel:[0,1,0] op_sel_hi:[1,1,1]" : "+v"(acc) : "v"(hp), "v"(wp))

// tanh(x) = 1 - 2*rcp(exp(2x)+1): ~1-2 ulp, exact at saturation. Validated R5-R12.
__device__ __forceinline__ float fast_tanh(float x) {
    float e = __expf(2.0f * x);
    return 1.0f - 2.0f * __builtin_amdgcn_rcpf(e + 1.0f);
}

__device__ __forceinline__ unsigned pick_remove(unsigned& el, int d) {
    unsigned v = (el >> (4 * d)) & 0xFu;
    unsigned low = el & ((1u << (4 * d)) - 1u);
    el = low | ((el >> (4 * (d + 1))) << (4 * d));
    return v;
}

// ---------------- fused: one block per batch element, 4 waves = 2 spin-pairs ----------------
// Each 128-thread half runs the R12-validated per-spin pipeline in its own LDS pool;
// jastrow terms computed during stage 1; t0 combines log|ps0*ps1| - jas inline.
// Kills the combine kernel + psum roundtrip (the only remaining addressable time:
// R8-R12 showed the antisym core is at a structural plateau ~104us).
__global__ __launch_bounds__(256, 1) void antisym_fused(
    const float* __restrict__ elec_pos, const float* __restrict__ ion_pos,
    const float* __restrict__ bf_w, const float* __restrict__ bf_b,
    const float* __restrict__ w0, const float* __restrict__ b0,
    const float* __restrict__ w1, const float* __restrict__ b1,
    const float* __restrict__ w2, const float* __restrict__ jk,
    float* __restrict__ out, int B)
{
    const int b = blockIdx.x;
    const int t = threadIdx.x;
    const int s = t >> 7;                   // spin: waves 0-1 -> 0, waves 2-3 -> 1
    const int ts = t & 127;                 // thread within the spin-pair
    const int wave = (t >> 6) & 1;          // wave within the spin-pair
    const int lane = t & 63;

    __shared__ __align__(16) float pool[NSPIN][POOL_WORDS];   // 2 x 31744 B
    __shared__ double red_h[NSPIN][2];
    __shared__ double red_j[NSPIN][2];
    __shared__ float jterm[2 * NELEC];

    float* s1e = pool[s];                                     // [160]    (stage A)
    #define GROW(j) (pool[s] + 160 + (j) * RS)                // G[j][.]  (stage A)
    #define HTROW(k) (pool[s] + (k) * HTS)                    // HT[k][.] (stage B)

    // ---- stage 1: stream_1e = tanh(feats @ bf_w + bf_b), this spin's 5 electrons ----
    const float* ep = elec_pos + (b * NELEC + s * NPER) * DIM;
    const float i0x = ion_pos[0], i0y = ion_pos[1], i0z = ion_pos[2];
    const float i1x = ion_pos[3], i1y = ion_pos[4], i1z = ion_pos[5];
    for (int idx = ts; idx < NPER * DP; idx += 128) {
        int j = idx >> 5, c = idx & 31;
        float ex = ep[j * 3 + 0], ey = ep[j * 3 + 1], ez = ep[j * 3 + 2];
        float dx0 = ex - i0x, dy0 = ey - i0y, dz0 = ez - i0z;
        float dx1 = ex - i1x, dy1 = ey - i1y, dz1 = ez - i1z;
        float n0 = sqrtf(dx0 * dx0 + dy0 * dy0 + dz0 * dz0);
        float n1 = sqrtf(dx1 * dx1 + dy1 * dy1 + dz1 * dz1);
        float acc = bf_b[c];
        acc += dx0 * bf_w[0 * DP + c];
        acc += dy0 * bf_w[1 * DP + c];
        acc += dz0 * bf_w[2 * DP + c];
        acc += dx1 * bf_w[3 * DP + c];
        acc += dy1 * bf_w[4 * DP + c];
        acc += dz1 * bf_w[5 * DP + c];
        acc += n0 * bf_w[6 * DP + c];
        acc += n1 * bf_w[7 * DP + c];
        s1e[idx] = fast_tanh(acc);
    }
    // jastrow terms (combine_kern's exact per-term math; summed e-major by t0 later)
    if (t < 2 * NELEC) {
        int e = t >> 1, ion = t & 1;
        const float* epb = elec_pos + b * NELEC * DIM;
        float ex = epb[e * 3 + 0], ey = epb[e * 3 + 1], ez = epb[e * 3 + 2];
        float ix = ion_pos[ion * 3 + 0], iy = ion_pos[ion * 3 + 1], iz = ion_pos[ion * 3 + 2];
        float dx = ex - ix, dy = ey - iy, dz = ez - iz;
        jterm[t] = jk[ion] * sqrtf(dx * dx + dy * dy + dz * dz);
    }
    __syncthreads();

    // ---- stage 2: G[j][i*64+c] = s1e[j][:] @ w0[s][32i:32i+32, c] (R5-R12 validated) ----
    const float* w0s = w0 + s * (NPER * DP) * NDENSE;   // [160][64]
    for (int j = wave; j < NPER; j += 2) {
        float4 sv4[8];
        #pragma unroll
        for (int q = 0; q < 8; q++) sv4[q] = *(const float4*)(s1e + j * DP + q * 4);
        #pragma unroll
        for (int i = 0; i < NPER; i++) {
            float acc = 0.f;
            #pragma unroll
            for (int q = 0; q < 8; q++) {
                const float* wb = w0s + (i * DP + q * 4) * NDENSE + lane;  // coalesced
                acc += sv4[q].x * wb[0 * NDENSE];
                acc += sv4[q].y * wb[1 * NDENSE];
                acc += sv4[q].z * wb[2 * NDENSE];
                acc += sv4[q].w * wb[3 * NDENSE];
            }
            GROW(j)[i * NDENSE + lane] = acc;
        }
    }
    __syncthreads();

    const float* b0s = b0 + s * NDENSE;
    const float* w2s = w2 + s * NDENSE;     // w2 is [s][64][1]

    // ---- stage 3 phase 1: lane = perm. h_p built in registers (G still live) ----
    const int pid = wave * 60 + lane;
    float sign = 0.f;
    int p0 = 0, p1 = 0, p2 = 0, p3 = 0, p4 = 0;
    if (lane < 60) {
        int p = pid;
        unsigned el = 0x43210u;
        int d0 = p / 24; p -= d0 * 24;
        int d1 = p / 6;  p -= d1 * 6;
        int d2 = p / 2;  p -= d2 * 2;
        int d3 = p;
        p0 = pick_remove(el, d0);
        p1 = pick_remove(el, d1);
        p2 = pick_remove(el, d2);
        p3 = pick_remove(el, d3);
        p4 = el & 0xF;
        sign = ((d0 + d1 + d2 + d3) & 1) ? -1.f : 1.f;
    }
    const float* g0 = GROW(p0) + 0 * NDENSE;
    const float* g1 = GROW(p1) + 1 * NDENSE;
    const float* g2 = GROW(p2) + 2 * NDENSE;
    const float* g3 = GROW(p3) + 3 * NDENSE;
    const float* g4 = GROW(p4) + 4 * NDENSE;

    float h[NDENSE];                        // constant-indexed -> VGPR-resident
    float hdot = 0.f;
    #pragma unroll
    for (int cc = 0; cc < NDENSE / 4; cc++) {
        float4 a = *(const float4*)(b0s + cc * 4);                    // uniform -> s_load
        float4 q;
        q = *(const float4*)(g0 + cc * 4); a.x += q.x; a.y += q.y; a.z += q.z; a.w += q.w;
        q = *(const float4*)(g1 + cc * 4); a.x += q.x; a.y += q.y; a.z += q.z; a.w += q.w;
        q = *(const float4*)(g2 + cc * 4); a.x += q.x; a.y += q.y; a.z += q.z; a.w += q.w;
        q = *(const float4*)(g3 + cc * 4); a.x += q.x; a.y += q.y; a.z += q.z; a.w += q.w;
        q = *(const float4*)(g4 + cc * 4); a.x += q.x; a.y += q.y; a.z += q.z; a.w += q.w;
        float t0 = fast_tanh(a.x), t1 = fast_tanh(a.y), t2 = fast_tanh(a.z), t3 = fast_tanh(a.w);
        h[cc * 4 + 0] = t0; h[cc * 4 + 1] = t1; h[cc * 4 + 2] = t2; h[cc * 4 + 3] = t3;
        hdot += t0 * w2s[cc * 4 + 0] + t1 * w2s[cc * 4 + 1]
              + t2 * w2s[cc * 4 + 2] + t3 * w2s[cc * 4 + 3];
    }

    double dvh = (double)(sign * hdot);     // sign=0 for lanes 60-63
    #pragma unroll
    for (int off = 32; off > 0; off >>= 1) dvh += __shfl_down(dvh, off, 64);
    if (lane == 0) red_h[s][wave] = dvh;

    __syncthreads();                        // all G reads complete -> pool reusable

    // park h transposed: HT[k][pid] (b32 writes, consecutive pids -> 2 lanes/bank = free)
    if (lane < 60) {
        #pragma unroll
        for (int k = 0; k < NDENSE; k++) HTROW(k)[pid] = h[k];
    }
    __syncthreads();                        // HT visible

    // ---- stage 3 phase 2: 8x8 tile GEMM V[120x64] = H @ W1, packed-fp32 FMA (R12) ----
    const int pg = lane >> 3, jg = lane & 7;
    const int pb = wave ? (56 + 8 * pg) : (8 * pg);
    const float* w1s = w1 + s * NDENSE * NDENSE;
    const float* b1s = b1 + s * NDENSE;
    const float* wgp = w1s + 8 * jg;        // this lane's j-octet in w1 row k

    v2f vp[4][8];
    #pragma unroll
    for (int ip = 0; ip < 4; ip++)
        #pragma unroll
        for (int r = 0; r < 8; r++) vp[ip][r] = (v2f)(0.f);

    v4f ha_n = *(const v4f*)(&HTROW(0)[pb]);
    v4f hb_n = *(const v4f*)(&HTROW(0)[pb + 4]);
    v4f wa_n = *(const v4f*)(wgp);
    v4f wb_n = *(const v4f*)(wgp + 4);
    #pragma unroll 4
    for (int k = 0; k < NDENSE; k++) {
        const v4f ha = ha_n, hb = hb_n, wa = wa_n, wb = wb_n;
        if (k + 1 < NDENSE) {               // R10-validated k+1 prefetch
            ha_n = *(const v4f*)(&HTROW(k + 1)[pb]);
            hb_n = *(const v4f*)(&HTROW(k + 1)[pb + 4]);
            wa_n = *(const v4f*)(wgp + (k + 1) * NDENSE);
            wb_n = *(const v4f*)(wgp + (k + 1) * NDENSE + 4);
        }
        v2f hp[4] = {ha.xy, ha.zw, hb.xy, hb.zw};   // perm pairs
        v2f wp[4] = {wa.xy, wa.zw, wb.xy, wb.zw};   // j pairs
        #pragma unroll
        for (int ip = 0; ip < 4; ip++) {
            PK_FMA_LO(vp[ip][0], hp[ip], wp[0]);
            PK_FMA_HI(vp[ip][1], hp[ip], wp[0]);
            PK_FMA_LO(vp[ip][2], hp[ip], wp[1]);
            PK_FMA_HI(vp[ip][3], hp[ip], wp[1]);
            PK_FMA_LO(vp[ip][4], hp[ip], wp[2]);
            PK_FMA_HI(vp[ip][5], hp[ip], wp[2]);
            PK_FMA_LO(vp[ip][6], hp[ip], wp[3]);
            PK_FMA_HI(vp[ip][7], hp[ip], wp[3]);
        }
    }

    // epilogue: lanesum = sum_i sgn_i * sum_r tanh(v[i][r]+b1[j]) * w2[j]
    float4 b1a = *(const float4*)(b1s + 8 * jg);
    float4 b1b = *(const float4*)(b1s + 8 * jg + 4);
    float4 w2a = *(const float4*)(w2s + 8 * jg);
    float4 w2b = *(const float4*)(w2s + 8 * jg + 4);
    const float b1v[8] = {b1a.x, b1a.y, b1a.z, b1a.w, b1b.x, b1b.y, b1b.z, b1b.w};
    const float w2v[8] = {w2a.x, w2a.y, w2a.z, w2a.w, w2b.x, w2b.y, w2b.z, w2b.w};

    float lanesum = 0.f;
    #pragma unroll
    for (int i = 0; i < 8; i++) {
        int p = pb + i;                      // Lehmer parity
        int d0 = p / 24;  int r0 = p - 24 * d0;
        int d1 = r0 / 6;  int r1 = r0 - 6 * d1;
        int d2 = r1 >> 1; int d3 = r1 & 1;
        float sgn = ((d0 + d1 + d2 + d3) & 1) ? -1.f : 1.f;
        if (wave == 1 && pg == 0) sgn = 0.f; // duplicate tile (perms 56-63)
        float si = 0.f;
        #pragma unroll
        for (int r = 0; r < 8; r++) {
            float vir = (i & 1) ? vp[i >> 1][r].y : vp[i >> 1][r].x;
            si = fmaf(fast_tanh(vir + b1v[r]), w2v[r], si);
        }
        lanesum = fmaf(sgn, si, lanesum);
    }

    double dvj = (double)lanesum;
    #pragma unroll
    for (int off = 32; off > 0; off >>= 1) dvj += __shfl_down(dvj, off, 64);
    if (lane == 0) red_j[s][wave] = dvj;
    __syncthreads();

    // ---- inline combine (R5-R12-validated product form + combine's e-major jastrow order) ----
    if (t == 0) {
        float ps0 = (float)((red_h[0][0] + red_h[0][1]) + (red_j[0][0] + red_j[0][1]));
        float ps1 = (float)((red_h[1][0] + red_h[1][1]) + (red_j[1][0] + red_j[1][1]));
        float jas = 0.f;
        #pragma unroll
        for (int i = 0; i < 2 * NELEC; i++) jas += jterm[i];
        out[b] = logf(fabsf(ps0 * ps1)) - jas;
    }
    // b2 omitted: sum_p sign_p = 0 kills it exactly.
}

extern "C" void kernel_launch(void* const* d_in, const int* in_sizes, int n_in,
                              void* d_out, int out_size, void* d_ws, size_t ws_size,
                              hipStream_t stream) {
    const float* elec_pos = (const float*)d_in[0];
    const float* ion_pos  = (const float*)d_in[1];
    const float* bf_w     = (const float*)d_in[2];
    const float* bf_b     = (const float*)d_in[3];
    const float* w0       = (const float*)d_in[4];
    const float* b0       = (const float*)d_in[5];
    const float* w1       = (const float*)d_in[6];
    const float* b1       = (const float*)d_in[7];
    const float* w2       = (const float*)d_in[8];
    const float* jk       = (const float*)d_in[10];
    float* out = (float*)d_out;

    const int B = in_sizes[0] / (NELEC * DIM);   // 2048

    hipLaunchKernelGGL(antisym_fused,
                       dim3(B), dim3(256), 0, stream,
                       elec_pos, ion_pos, bf_w, bf_b, w0, b0, w1, b1, w2, jk, out, B);
}